// Round 8
// baseline (284.105 us; speedup 1.0000x reference)
//
#include <hip/hip_runtime.h>

// VQ-VAE forward, 3-phase:
//   init: zero keys/counts/cells, pre-swizzle W -> bf16 (ws), wnh = 0.25-||w||^2/2
//   scan: token-group x K-half blocks; B staged LDS via global_load_lds;
//         packed (score&~31)|(31-ct) u32 max scan; u64 atomicMax per-token key.
//   out : decode keys, gather W fp32, NT-store out, counts/SSE, fused finalize.
//
// score'(t,c) = dot(x,w) + (0.25 - ||w||^2/2) in (0.15,0.35) > 0
// dist = xsq + 0.5 - 2*score' ; SSE = sum(xsq) [scan] + sum(0.5-2*score') [out]
//
// ws: 0 u32 counts[1024] | 4096 f64 sseA | 4104 f64 sseB | 4112 u32 done
//     8192 f32 wnh[1024] | 16384 uint4 wbf[8192] (128KB) | 147456 u64 keys[131072]

typedef __bf16 bf16x8 __attribute__((ext_vector_type(8)));
typedef float  f32x4  __attribute__((ext_vector_type(4)));

constexpr int D = 64;
constexpr int K = 1024;
constexpr float CSHIFT = 0.25f;

__global__ __launch_bounds__(256) void vq_init(const float* __restrict__ W,
                                               unsigned* __restrict__ counts,
                                               float* __restrict__ wnh,
                                               unsigned long long* __restrict__ keys,
                                               double* __restrict__ sseA,
                                               double* __restrict__ sseB,
                                               unsigned* __restrict__ done,
                                               uint4* __restrict__ wbf) {
  const int t = blockIdx.x * 256 + threadIdx.x;  // 0..131071 (grid 512)
  keys[t] = 0ull;                                // real keys always > 0
  if (t < K) {
    const float4* row = reinterpret_cast<const float4*>(W + t * D);
    float s = 0.f;
#pragma unroll
    for (int p = 0; p < 8; ++p) {
      float4 v0 = row[2 * p], v1 = row[2 * p + 1];
      s = fmaf(v0.x, v0.x, s); s = fmaf(v0.y, v0.y, s);
      s = fmaf(v0.z, v0.z, s); s = fmaf(v0.w, v0.w, s);
      s = fmaf(v1.x, v1.x, s); s = fmaf(v1.y, v1.y, s);
      s = fmaf(v1.z, v1.z, s); s = fmaf(v1.w, v1.w, s);
      bf16x8 pk;
      pk[0] = (__bf16)v0.x; pk[1] = (__bf16)v0.y; pk[2] = (__bf16)v0.z; pk[3] = (__bf16)v0.w;
      pk[4] = (__bf16)v1.x; pk[5] = (__bf16)v1.y; pk[6] = (__bf16)v1.z; pk[7] = (__bf16)v1.w;
      const int slot = (t >> 4) * 128 + (p >> 2) * 64 + (p & 3) * 16 + (t & 15);
      wbf[slot] = __builtin_bit_cast(uint4, pk);
    }
    wnh[t] = CSHIFT - 0.5f * s;
    counts[t] = 0u;
  }
  if (t == 0) { *sseA = 0.0; *sseB = 0.0; *done = 0u; }
}

__device__ __forceinline__ void scan16(const uint4* s_w, const float* wreg,
                                       const bf16x8 (&afrag)[4][2],
                                       unsigned (&bestp)[4][4],
                                       int baseor, int lane) {
#pragma unroll
  for (int ct = 0; ct < 16; ++ct) {
    const float w0 = wreg[ct];
    bf16x8 b0 = __builtin_bit_cast(bf16x8, s_w[ct * 128 + lane]);       // dims 0..31
    bf16x8 b1 = __builtin_bit_cast(bf16x8, s_w[ct * 128 + 64 + lane]);  // dims 32..63
    const unsigned orc = (unsigned)(baseor - ct);  // 31 - (chunk*16+ct)
#pragma unroll
    for (int tt = 0; tt < 4; ++tt) {
      f32x4 acc = {w0, w0, w0, w0};  // C init = 0.25 - ||w||^2/2
      acc = __builtin_amdgcn_mfma_f32_16x16x32_bf16(afrag[tt][0], b0, acc, 0, 0, 0);
      acc = __builtin_amdgcn_mfma_f32_16x16x32_bf16(afrag[tt][1], b1, acc, 0, 0, 0);
#pragma unroll
      for (int j = 0; j < 4; ++j) {
        // (score & ~31) | (31-ct): 32-ulp quantum ~1e-6, ties -> smaller ct
        unsigned pb = (__builtin_bit_cast(unsigned, acc[j]) & 0xFFFFFFE0u) | orc;
        bestp[tt][j] = max(bestp[tt][j], pb);
      }
    }
  }
}

// 256 thr = 4 waves x 64 tokens; blockIdx: bit0 = K-half, rest = token group.
__global__ __launch_bounds__(256, 4) void vq_scan(const float* __restrict__ x,
                                                  const uint4* __restrict__ wbf,
                                                  const float* __restrict__ wnh,
                                                  unsigned long long* __restrict__ keys,
                                                  double* __restrict__ sseA) {
  __shared__ uint4 s_w[2048];  // 32 KB = 256 codes

  const int tid = threadIdx.x;
  const int wv = tid >> 6, lane = tid & 63;
  const int g = lane >> 4, nl = lane & 15;
  const int khalf = blockIdx.x & 1;
  const int tokbase = (blockIdx.x >> 1) * 256 + wv * 64;
  const int cb0 = khalf * 512;

  // A fragments: lane holds A[m=nl][k=g*8+j]; 4 token tiles x 2 k-halves.
  bf16x8 afrag[4][2];
  float xsq = 0.f;
#pragma unroll
  for (int tt = 0; tt < 4; ++tt) {
#pragma unroll
    for (int s = 0; s < 2; ++s) {
      const float* px = x + (size_t)(tokbase + tt * 16 + nl) * D + s * 32 + g * 8;
      float4 v0 = *reinterpret_cast<const float4*>(px);
      float4 v1 = *reinterpret_cast<const float4*>(px + 4);
      xsq = fmaf(v0.x, v0.x, xsq); xsq = fmaf(v0.y, v0.y, xsq);
      xsq = fmaf(v0.z, v0.z, xsq); xsq = fmaf(v0.w, v0.w, xsq);
      xsq = fmaf(v1.x, v1.x, xsq); xsq = fmaf(v1.y, v1.y, xsq);
      xsq = fmaf(v1.z, v1.z, xsq); xsq = fmaf(v1.w, v1.w, xsq);
      bf16x8 pk;
      pk[0] = (__bf16)v0.x; pk[1] = (__bf16)v0.y; pk[2] = (__bf16)v0.z; pk[3] = (__bf16)v0.w;
      pk[4] = (__bf16)v1.x; pk[5] = (__bf16)v1.y; pk[6] = (__bf16)v1.z; pk[7] = (__bf16)v1.w;
      afrag[tt][s] = pk;
    }
  }

  // Stage chunk 0 (codes cb0..cb0+255) + wnh regs; both drained by the barrier.
#pragma unroll
  for (int it = 0; it < 8; ++it)
    __builtin_amdgcn_global_load_lds(
        (const __attribute__((address_space(1))) unsigned*)(wbf + (size_t)cb0 * 8 + it * 256 + wv * 64 + lane),
        (__attribute__((address_space(3))) unsigned*)(&s_w[it * 256 + wv * 64]),
        16, 0, 0);
  float wreg[16];
#pragma unroll
  for (int ct = 0; ct < 16; ++ct) wreg[ct] = wnh[cb0 + ct * 16 + nl];
  __syncthreads();

  unsigned bestp[4][4];
#pragma unroll
  for (int tt = 0; tt < 4; ++tt)
#pragma unroll
    for (int j = 0; j < 4; ++j) bestp[tt][j] = 0u;

  scan16(s_w, wreg, afrag, bestp, 31, lane);
  __syncthreads();  // chunk 0 consumed

  // Stage chunk 1 (codes cb0+256..cb0+511).
#pragma unroll
  for (int it = 0; it < 8; ++it)
    __builtin_amdgcn_global_load_lds(
        (const __attribute__((address_space(1))) unsigned*)(wbf + (size_t)cb0 * 8 + 2048 + it * 256 + wv * 64 + lane),
        (__attribute__((address_space(3))) unsigned*)(&s_w[it * 256 + wv * 64]),
        16, 0, 0);
#pragma unroll
  for (int ct = 0; ct < 16; ++ct) wreg[ct] = wnh[cb0 + 256 + ct * 16 + nl];
  __syncthreads();

  scan16(s_w, wreg, afrag, bestp, 15, lane);

  // Per-element cross-lane max over the 16 columns, then u64 key atomicMax.
#pragma unroll
  for (int tt = 0; tt < 4; ++tt) {
#pragma unroll
    for (int j = 0; j < 4; ++j) {
      unsigned p = bestp[tt][j], m = p;
#pragma unroll
      for (int off = 1; off < 16; off <<= 1)
        m = max(m, (unsigned)__shfl_xor((int)m, off, 64));
      if (p == m) {  // winning lane(s); ties resolved by key (smaller code wins)
        const int ctid = 31 - (int)(p & 31u);
        const int code = ((khalf * 32 + ctid) << 4) | nl;
        const int tok = tokbase + tt * 16 + 4 * g + j;
        const unsigned long long key =
            ((unsigned long long)(p & 0xFFFFFFE0u) << 10) |
            (unsigned long long)(1023 - code);
        atomicMax(&keys[tok], key);
      }
    }
  }

  // sum(x^2): K-half 0 blocks only (each (tok,dim) once per wave).
  if (khalf == 0) {
#pragma unroll
    for (int off = 32; off > 0; off >>= 1) xsq += __shfl_down(xsq, off, 64);
    if (lane == 0) atomicAdd(sseA, (double)xsq);
  }
}

// Pure streaming epilogue: 1024 blocks x 256 thr; 16 tokens/block/iter x 8.
__global__ __launch_bounds__(256) void vq_out(const float* __restrict__ Wf,
                                              const unsigned long long* __restrict__ keys,
                                              unsigned* __restrict__ counts,
                                              double* __restrict__ sseA,
                                              double* __restrict__ sseB,
                                              unsigned* __restrict__ done,
                                              float* __restrict__ out,
                                              int nblocks, int n_tokens) {
  __shared__ double s_s[4];
  __shared__ double sdd[4];
  __shared__ int sui[4];
  __shared__ unsigned s_lastf;

  const int tid = threadIdx.x;
  const int wv = tid >> 6, lane = tid & 63;
  const int d4 = tid & 15, row = tid >> 4;

  float part = 0.f;
#pragma unroll
  for (int it = 0; it < 8; ++it) {
    const int tok = (blockIdx.x * 8 + it) * 16 + row;
    const unsigned long long key = keys[tok];  // 16-lane broadcast, L2
    const unsigned code = 1023u - (unsigned)(key & 1023u);
    f32x4 q = *reinterpret_cast<const f32x4*>(Wf + code * D + d4 * 4);
    __builtin_nontemporal_store(q,
        reinterpret_cast<f32x4*>(out + (size_t)tok * D + d4 * 4));
    if (d4 == 0) {
      atomicAdd(&counts[code], 1u);
      const float sc = __builtin_bit_cast(float, (unsigned)(key >> 10));
      part += fmaf(-2.0f, sc, 0.5f);  // dist - xsq
    }
  }
  part += __shfl_down(part, 32, 64);
  part += __shfl_down(part, 16, 64);
  if (lane == 0) s_s[wv] = part;
  __syncthreads();  // drains all waves' atomics/stores (vmcnt 0 at barrier)
  if (tid == 0) {
    atomicAdd(sseB, (s_s[0] + s_s[1]) + (s_s[2] + s_s[3]));
    __builtin_amdgcn_s_waitcnt(0);
    unsigned r = __hip_atomic_fetch_add(done, 1u, __ATOMIC_RELAXED,
                                        __HIP_MEMORY_SCOPE_AGENT);
    s_lastf = (r == (unsigned)(nblocks - 1)) ? 1u : 0u;
  }
  __syncthreads();

  if (s_lastf) {  // last-finishing block: loss / perplexity / usage
    double dsum = 0.0;
    int usum = 0;
    const float inv = 1.0f / (float)n_tokens;
    for (int i = tid; i < K; i += 256) {
      unsigned c = atomicAdd(&counts[i], 0u);  // coherent RMW read
      float pr = (float)c * inv;
      dsum += (double)(pr * logf(pr + 1e-10f));
      usum += (c >= 1u) ? 1 : 0;
    }
#pragma unroll
    for (int off = 32; off > 0; off >>= 1) {
      dsum += __shfl_down(dsum, off, 64);
      usum += __shfl_down(usum, off, 64);
    }
    if (lane == 0) { sdd[wv] = dsum; sui[wv] = usum; }
    __syncthreads();
    if (tid == 0) {
      double s2 = (sdd[0] + sdd[1]) + (sdd[2] + sdd[3]);
      int u2 = (sui[0] + sui[1]) + (sui[2] + sui[3]);
      double sa = atomicAdd(sseA, 0.0);
      double sb = atomicAdd(sseB, 0.0);
      double mean = (sa + sb) / ((double)n_tokens * (double)D);
      float* tail = out + (size_t)n_tokens * D;
      tail[0] = 3.0f * (float)mean;  // q_latent + 2*e_latent
      tail[1] = expf(-(float)s2);    // perplexity
      tail[2] = (float)u2;           // usage
    }
  }
}

extern "C" void kernel_launch(void* const* d_in, const int* in_sizes, int n_in,
                              void* d_out, int out_size, void* d_ws, size_t ws_size,
                              hipStream_t stream) {
  const float* x = (const float*)d_in[0];
  const float* W = (const float*)d_in[1];
  float* out = (float*)d_out;

  unsigned* counts = (unsigned*)d_ws;
  double* sseA = (double*)((char*)d_ws + 4096);
  double* sseB = (double*)((char*)d_ws + 4104);
  unsigned* done = (unsigned*)((char*)d_ws + 4112);
  float* wnh = (float*)((char*)d_ws + 8192);
  uint4* wbf = (uint4*)((char*)d_ws + 16384);
  unsigned long long* keys = (unsigned long long*)((char*)d_ws + 147456);

  const int n_tokens = in_sizes[0] / D;  // 131072

  vq_init<<<n_tokens / 256, 256, 0, stream>>>(W, counts, wnh, keys, sseA, sseB, done, wbf);
  vq_scan<<<(n_tokens / 256) * 2, 256, 0, stream>>>(x, wbf, wnh, keys, sseA);
  vq_out<<<n_tokens / 128, 256, 0, stream>>>(W, keys, counts, sseA, sseB, done, out,
                                             n_tokens / 128, n_tokens);
}